// Round 1
// 760.840 us; speedup vs baseline: 1.0544x; 1.0544x over previous
//
#include <hip/hip_runtime.h>
#include <hip/hip_bf16.h>

typedef unsigned short u16;
typedef unsigned int u32;

#define NN 10000
#define EE 320000

typedef __attribute__((ext_vector_type(8))) short short8;
typedef __attribute__((ext_vector_type(4))) float f32x4;

__device__ __forceinline__ u16 f2bfu(float f) {
    u32 x = __float_as_uint(f);
    x += 0x7FFFu + ((x >> 16) & 1u);   // round-to-nearest-even
    return (u16)(x >> 16);
}
__device__ __forceinline__ float bfu2f(u16 u) { return __uint_as_float(((u32)u) << 16); }
__device__ __forceinline__ void ld4f(const float* p, float* o) {
    float4 v = *(const float4*)p; o[0] = v.x; o[1] = v.y; o[2] = v.z; o[3] = v.w;
}

// ---------------- CSR build ----------------
__global__ void k_hist(const int* __restrict__ dst, int* __restrict__ cnt) {
    int e = blockIdx.x * 256 + threadIdx.x;
    if (e < EE) atomicAdd(&cnt[dst[e]], 1);
}

__global__ void k_dinv(const int* __restrict__ cnt, float* __restrict__ dinv) {
    int n = blockIdx.x * 256 + threadIdx.x;
    if (n < NN) dinv[n] = 1.f / sqrtf((float)(cnt[n] + 1));  // +1 self loop; deg>=1 always
}

__global__ void k_scan(const int* __restrict__ cnt, int* __restrict__ rowptr) {
    __shared__ int sh[1024];
    int t = threadIdx.x;
    int base = t * 10;
    int loc[10];
    int s = 0;
    #pragma unroll
    for (int i = 0; i < 10; i++) {
        int idx = base + i;
        int v = (idx < NN) ? cnt[idx] : 0;
        loc[i] = s; s += v;
    }
    sh[t] = s;
    __syncthreads();
    for (int off = 1; off < 1024; off <<= 1) {
        int v = (t >= off) ? sh[t - off] : 0;
        __syncthreads();
        sh[t] += v;
        __syncthreads();
    }
    int ex = sh[t] - s;   // exclusive base for this thread's chunk
    #pragma unroll
    for (int i = 0; i < 10; i++) {
        int idx = base + i;
        if (idx < NN) rowptr[idx] = ex + loc[i];
    }
    if (t == 0) rowptr[NN] = EE;
}

__global__ void k_scatter(const int* __restrict__ src, const int* __restrict__ dst,
                          const int* __restrict__ rowptr, int* __restrict__ fill,
                          int* __restrict__ csr) {
    int e = blockIdx.x * 256 + threadIdx.x;
    if (e < EE) {
        int d = dst[e];
        int pos = rowptr[d] + atomicAdd(&fill[d], 1);
        csr[pos] = src[e];
    }
}

// ---------------- generic dense layer: out[N,M] = act(A[N,K] @ W[K,M] + b) ----------------
// wave handles 4 rows; lane covers cols {lane + 64*j}. OB16: output bf16 (u16) instead of fp32.
template <int K, int M, bool RELU, bool BIAS, bool OB16>
__global__ __launch_bounds__(256) void k_linear(const float* __restrict__ A, const float* __restrict__ W,
                                                const float* __restrict__ Bb, void* __restrict__ outv) {
    constexpr int MC = M / 64;
    int wid = (blockIdx.x * blockDim.x + threadIdx.x) >> 6;
    int lane = threadIdx.x & 63;
    int row0 = wid * 4;
    if (row0 >= NN) return;
    float acc[4][MC];
    #pragma unroll
    for (int i = 0; i < 4; i++)
        #pragma unroll
        for (int j = 0; j < MC; j++) acc[i][j] = 0.f;
    for (int k = 0; k < K; k += 4) {
        float a[4][4];
        #pragma unroll
        for (int i = 0; i < 4; i++) ld4f(A + (size_t)(row0 + i) * K + k, a[i]);
        #pragma unroll
        for (int kk = 0; kk < 4; kk++) {
            float wv[MC];
            #pragma unroll
            for (int j = 0; j < MC; j++) wv[j] = W[(size_t)(k + kk) * M + j * 64 + lane];
            #pragma unroll
            for (int i = 0; i < 4; i++)
                #pragma unroll
                for (int j = 0; j < MC; j++) acc[i][j] += a[i][kk] * wv[j];
        }
    }
    float* outf = (float*)outv;
    u16*   outb = (u16*)outv;
    #pragma unroll
    for (int i = 0; i < 4; i++) {
        int r = row0 + i;
        #pragma unroll
        for (int j = 0; j < MC; j++) {
            float v = acc[i][j];
            if constexpr (BIAS) v += Bb[j * 64 + lane];
            if constexpr (RELU) v = fmaxf(v, 0.f);
            if constexpr (OB16) outb[(size_t)r * M + j * 64 + lane] = f2bfu(v);
            else                outf[(size_t)r * M + j * 64 + lane] = v;
        }
    }
}

// ---------------- GCN aggregation (bf16 gather input, fp32 output) ----------------
// lane covers dims {2*lane, 2*lane+1}; per edge one dword gather per lane (256B/edge/wave).
__global__ __launch_bounds__(256) void k_gcn_agg(const u16* __restrict__ h0, const int* __restrict__ rowptr,
                                                 const int* __restrict__ csr, const float* __restrict__ dinv,
                                                 const float* __restrict__ bias, float* __restrict__ h1) {
    int node = (blockIdx.x * blockDim.x + threadIdx.x) >> 6;
    int lane = threadIdx.x & 63;
    if (node >= NN) return;
    float di = dinv[node];
    u32 sv = *(const u32*)(h0 + (size_t)node * 128 + lane * 2);
    float acc0 = bfu2f((u16)(sv & 0xffffu)) * di * di;   // self loop
    float acc1 = bfu2f((u16)(sv >> 16)) * di * di;
    int st = rowptr[node], en = rowptr[node + 1];
    for (int p = st; p < en; p++) {
        int s = csr[p];
        float w = dinv[s] * di;
        u32 gv = *(const u32*)(h0 + (size_t)s * 128 + lane * 2);
        acc0 += bfu2f((u16)(gv & 0xffffu)) * w;
        acc1 += bfu2f((u16)(gv >> 16)) * w;
    }
    acc0 = fmaxf(acc0 + bias[lane * 2], 0.f);
    acc1 = fmaxf(acc1 + bias[lane * 2 + 1], 0.f);
    float2 o; o.x = acc0; o.y = acc1;
    *(float2*)(h1 + (size_t)node * 128 + lane * 2) = o;
}

// ---------------- GAT linear: g(bf16) + attention scores fused ----------------
// lane covers cols {lane*8 .. lane*8+7} (head = lane>>4, dims (lane&15)*8..+7).
// Scores computed from fp32 accumulators; g emitted bf16 for the aggregation gather.
__global__ __launch_bounds__(256) void k_gat_linear(const float* __restrict__ A, const float* __restrict__ W,
                                                    const float* __restrict__ att_s, const float* __restrict__ att_d,
                                                    u16* __restrict__ gbf, float* __restrict__ a_src,
                                                    float* __restrict__ a_dst) {
    int wid = (blockIdx.x * blockDim.x + threadIdx.x) >> 6;
    int lane = threadIdx.x & 63;
    int row0 = wid * 4;
    if (row0 >= NN) return;
    float acc[4][8];
    #pragma unroll
    for (int i = 0; i < 4; i++)
        #pragma unroll
        for (int t = 0; t < 8; t++) acc[i][t] = 0.f;
    for (int k = 0; k < 128; k += 4) {
        float a[4][4];
        #pragma unroll
        for (int i = 0; i < 4; i++) ld4f(A + (size_t)(row0 + i) * 128 + k, a[i]);
        #pragma unroll
        for (int kk = 0; kk < 4; kk++) {
            float wv[8];
            ld4f(W + (size_t)(k + kk) * 512 + lane * 8, wv);
            ld4f(W + (size_t)(k + kk) * 512 + lane * 8 + 4, wv + 4);
            #pragma unroll
            for (int i = 0; i < 4; i++)
                #pragma unroll
                for (int t = 0; t < 8; t++) acc[i][t] += a[i][kk] * wv[t];
        }
    }
    float sv[8], dv[8];
    ld4f(att_s + lane * 8, sv); ld4f(att_s + lane * 8 + 4, sv + 4);
    ld4f(att_d + lane * 8, dv); ld4f(att_d + lane * 8 + 4, dv + 4);
    int head = lane >> 4;
    #pragma unroll
    for (int i = 0; i < 4; i++) {
        int r = row0 + i;
        short8 pk;
        #pragma unroll
        for (int t = 0; t < 8; t++) pk[t] = (short)f2bfu(acc[i][t]);
        *(short8*)(gbf + (size_t)r * 512 + lane * 8) = pk;
        float ps = 0.f, pd = 0.f;
        #pragma unroll
        for (int t = 0; t < 8; t++) { ps += acc[i][t] * sv[t]; pd += acc[i][t] * dv[t]; }
        #pragma unroll
        for (int off = 1; off < 16; off <<= 1) {
            ps += __shfl_xor(ps, off, 64);
            pd += __shfl_xor(pd, off, 64);
        }
        if ((lane & 15) == i) {
            a_src[r * 4 + head] = ps;
            a_dst[r * 4 + head] = pd;
        }
    }
}

// ---------------- GAT softmax over incoming edges ----------------
__global__ __launch_bounds__(256) void k_gat_softmax(const int* __restrict__ rowptr, const int* __restrict__ csr,
                                                     const float* __restrict__ a_src, const float* __restrict__ a_dst,
                                                     float* __restrict__ alpha, float* __restrict__ selfalpha) {
    int node = (blockIdx.x * blockDim.x + threadIdx.x) >> 6;
    int lane = threadIdx.x & 63;
    if (node >= NN) return;
    float ad[4], asn[4];
    ld4f(a_dst + node * 4, ad);
    ld4f(a_src + node * 4, asn);
    float es[4], m[4];
    #pragma unroll
    for (int h = 0; h < 4; h++) {
        float e = asn[h] + ad[h];
        es[h] = e > 0.f ? e : 0.2f * e;   // self-loop score
        m[h] = es[h];                      // max is idempotent: every lane can seed with it
    }
    int st = rowptr[node], en = rowptr[node + 1];
    for (int p = st + lane; p < en; p += 64) {
        int s = csr[p];
        float as[4]; ld4f(a_src + s * 4, as);
        #pragma unroll
        for (int h = 0; h < 4; h++) {
            float e = as[h] + ad[h];
            e = e > 0.f ? e : 0.2f * e;
            m[h] = fmaxf(m[h], e);
        }
    }
    #pragma unroll
    for (int h = 0; h < 4; h++)
        for (int off = 1; off < 64; off <<= 1) m[h] = fmaxf(m[h], __shfl_xor(m[h], off, 64));
    float den[4];
    #pragma unroll
    for (int h = 0; h < 4; h++) den[h] = (lane == 0) ? __expf(es[h] - m[h]) : 0.f;  // self counted once
    for (int p = st + lane; p < en; p += 64) {
        int s = csr[p];
        float as[4]; ld4f(a_src + s * 4, as);
        #pragma unroll
        for (int h = 0; h < 4; h++) {
            float e = as[h] + ad[h];
            e = e > 0.f ? e : 0.2f * e;
            den[h] += __expf(e - m[h]);
        }
    }
    #pragma unroll
    for (int h = 0; h < 4; h++)
        for (int off = 1; off < 64; off <<= 1) den[h] += __shfl_xor(den[h], off, 64);
    float inv[4];
    #pragma unroll
    for (int h = 0; h < 4; h++) inv[h] = 1.f / den[h];
    for (int p = st + lane; p < en; p += 64) {
        int s = csr[p];
        float as[4]; ld4f(a_src + s * 4, as);
        float4 al;
        float av[4];
        #pragma unroll
        for (int h = 0; h < 4; h++) {
            float e = as[h] + ad[h];
            e = e > 0.f ? e : 0.2f * e;
            av[h] = __expf(e - m[h]) * inv[h];
        }
        al.x = av[0]; al.y = av[1]; al.z = av[2]; al.w = av[3];
        *(float4*)(alpha + (size_t)p * 4) = al;
    }
    if (lane == 0) {
        float4 sa;
        sa.x = __expf(es[0] - m[0]) * inv[0];
        sa.y = __expf(es[1] - m[1]) * inv[1];
        sa.z = __expf(es[2] - m[2]) * inv[2];
        sa.w = __expf(es[3] - m[3]) * inv[3];
        *(float4*)(selfalpha + (size_t)node * 4) = sa;
    }
}

// ---------------- GAT aggregation (bf16 gather, mean over heads) ----------------
// lane gathers one short8 (head lane>>4, dims (lane&15)*8..+7) per edge: 1KB/edge/wave.
__global__ __launch_bounds__(256) void k_gat_agg(const u16* __restrict__ gbf, const int* __restrict__ rowptr,
                                                 const int* __restrict__ csr, const float* __restrict__ alpha,
                                                 const float* __restrict__ selfalpha, const float* __restrict__ bias,
                                                 float* __restrict__ h2) {
    int node = (blockIdx.x * blockDim.x + threadIdx.x) >> 6;
    int lane = threadIdx.x & 63;
    if (node >= NN) return;
    int head = lane >> 4;
    float acc[8];
    float sa = selfalpha[(size_t)node * 4 + head];
    short8 gs = *(const short8*)(gbf + (size_t)node * 512 + lane * 8);
    #pragma unroll
    for (int t = 0; t < 8; t++) acc[t] = sa * bfu2f((u16)gs[t]);
    int st = rowptr[node], en = rowptr[node + 1];
    for (int p = st; p < en; p++) {
        int s = csr[p];
        float al = alpha[(size_t)p * 4 + head];
        short8 gv = *(const short8*)(gbf + (size_t)s * 512 + lane * 8);
        #pragma unroll
        for (int t = 0; t < 8; t++) acc[t] += al * bfu2f((u16)gv[t]);
    }
    // mean over heads: lanes {l, l^16, l^32, l^48} hold the same dims for the 4 heads
    #pragma unroll
    for (int t = 0; t < 8; t++) {
        acc[t] += __shfl_xor(acc[t], 16, 64);
        acc[t] += __shfl_xor(acc[t], 32, 64);
    }
    if (lane < 16) {
        int d0 = lane * 8;
        float o[8];
        #pragma unroll
        for (int t = 0; t < 8; t++) o[t] = fmaxf(acc[t] * 0.25f + bias[d0 + t], 0.f);
        float4 v0, v1;
        v0.x = o[0]; v0.y = o[1]; v0.z = o[2]; v0.w = o[3];
        v1.x = o[4]; v1.y = o[5]; v1.z = o[6]; v1.w = o[7];
        *(float4*)(h2 + (size_t)node * 128 + d0) = v0;
        *(float4*)(h2 + (size_t)node * 128 + d0 + 4) = v1;
    }
}

// ---------------- fused heads: mu, logvar (unclipped out), z ----------------
__global__ __launch_bounds__(256) void k_heads(const float* __restrict__ A, const float* __restrict__ muW,
                                               const float* __restrict__ muB, const float* __restrict__ lvW,
                                               const float* __restrict__ lvB, const float* __restrict__ eps,
                                               float* __restrict__ mu_out, float* __restrict__ lv_out,
                                               float* __restrict__ z) {
    int wid = (blockIdx.x * blockDim.x + threadIdx.x) >> 6;
    int lane = threadIdx.x & 63;
    int row0 = wid * 4;
    if (row0 >= NN) return;
    float am[4] = {0.f, 0.f, 0.f, 0.f};
    float av[4] = {0.f, 0.f, 0.f, 0.f};
    for (int k = 0; k < 128; k += 4) {
        float a[4][4];
        #pragma unroll
        for (int i = 0; i < 4; i++) ld4f(A + (size_t)(row0 + i) * 128 + k, a[i]);
        #pragma unroll
        for (int kk = 0; kk < 4; kk++) {
            float wm = muW[(k + kk) * 64 + lane];
            float wl = lvW[(k + kk) * 64 + lane];
            #pragma unroll
            for (int i = 0; i < 4; i++) { am[i] += a[i][kk] * wm; av[i] += a[i][kk] * wl; }
        }
    }
    float bm = muB[lane], bl = lvB[lane];
    #pragma unroll
    for (int i = 0; i < 4; i++) {
        size_t idx = (size_t)(row0 + i) * 64 + lane;
        float mu = am[i] + bm;
        float lv = av[i] + bl;
        mu_out[idx] = mu;
        lv_out[idx] = lv;                               // unclipped logvar is the output
        float c = fminf(fmaxf(lv, -10.f), 10.f);
        z[idx] = mu + eps[idx] * __expf(0.5f * c);
    }
}

// ---------------- decoder layer 2 + residual -> bf16 d ----------------
__global__ __launch_bounds__(256) void k_dec2(const float* __restrict__ A, const float* __restrict__ W,
                                              const float* __restrict__ Bb, const float* __restrict__ z,
                                              u16* __restrict__ dbf) {
    int wid = (blockIdx.x * blockDim.x + threadIdx.x) >> 6;
    int lane = threadIdx.x & 63;
    int row0 = wid * 4;
    if (row0 >= NN) return;
    float acc[4] = {0.f, 0.f, 0.f, 0.f};
    for (int k = 0; k < 128; k += 4) {
        float a[4][4];
        #pragma unroll
        for (int i = 0; i < 4; i++) ld4f(A + (size_t)(row0 + i) * 128 + k, a[i]);
        #pragma unroll
        for (int kk = 0; kk < 4; kk++) {
            float wv = W[(k + kk) * 64 + lane];
            #pragma unroll
            for (int i = 0; i < 4; i++) acc[i] += a[i][kk] * wv;
        }
    }
    float b = Bb[lane];
    #pragma unroll
    for (int i = 0; i < 4; i++) {
        size_t idx = (size_t)(row0 + i) * 64 + lane;
        dbf[idx] = f2bfu(acc[i] + b + z[idx]);
    }
}

// ---------------- logits = d @ d^T via MFMA bf16, fp32 output ----------------
// block 256 threads = 4 waves; block computes a 128x128 output tile; each wave 64x64.
__global__ __launch_bounds__(256) void k_logits(const u16* __restrict__ dbf, float* __restrict__ out) {
    __shared__ float tile[64][132];   // half-tile (64 rows), +4 pad keeps float4 alignment
    int tid = threadIdx.x;
    int wave = tid >> 6;
    int lane = tid & 63;
    int l15 = lane & 15, quad = lane >> 4;
    int rowhalf = wave >> 1;          // which 64-row half this wave computes
    int i0 = blockIdx.y * 128 + rowhalf * 64;
    int j0 = blockIdx.x * 128 + (wave & 1) * 64;

    f32x4 acc[4][4];
    #pragma unroll
    for (int r = 0; r < 4; r++)
        #pragma unroll
        for (int c = 0; c < 4; c++) acc[r][c] = (f32x4){0.f, 0.f, 0.f, 0.f};

    #pragma unroll
    for (int ks = 0; ks < 64; ks += 32) {
        short8 a[4], b[4];
        #pragma unroll
        for (int r = 0; r < 4; r++) {
            int row = i0 + r * 16 + l15;
            if (row < NN) a[r] = *(const short8*)(dbf + (size_t)row * 64 + ks + quad * 8);
            else a[r] = (short8){0, 0, 0, 0, 0, 0, 0, 0};
        }
        #pragma unroll
        for (int c = 0; c < 4; c++) {
            int row = j0 + c * 16 + l15;
            if (row < NN) b[c] = *(const short8*)(dbf + (size_t)row * 64 + ks + quad * 8);
            else b[c] = (short8){0, 0, 0, 0, 0, 0, 0, 0};
        }
        #pragma unroll
        for (int r = 0; r < 4; r++)
            #pragma unroll
            for (int c = 0; c < 4; c++)
                acc[r][c] = __builtin_amdgcn_mfma_f32_16x16x32_bf16(a[r], b[c], acc[r][c], 0, 0, 0);
    }

    // two chunks of 64 rows: fragments -> LDS (fp32) -> coalesced float4 nontemporal stores
    int lc0 = (wave & 1) * 64;
    #pragma unroll
    for (int chunk = 0; chunk < 2; chunk++) {
        if (rowhalf == chunk) {
            // C layout: row_in_16 = quad*4 + v, col_in_16 = l15
            #pragma unroll
            for (int r = 0; r < 4; r++)
                #pragma unroll
                for (int c = 0; c < 4; c++)
                    #pragma unroll
                    for (int v = 0; v < 4; v++)
                        tile[r * 16 + quad * 4 + v][lc0 + c * 16 + l15] = acc[r][c][v];
        }
        __syncthreads();
        // 64 rows x 128 cols fp32 = 2048 float4 chunks; 8 per thread
        #pragma unroll
        for (int it = 0; it < 8; it++) {
            int idx = it * 256 + tid;
            int row = idx >> 5, ch = idx & 31;
            int rg = blockIdx.y * 128 + chunk * 64 + row;
            int cg = blockIdx.x * 128 + ch * 4;
            if (rg < NN && cg < NN) {   // NN % 4 == 0: chunk never straddles the edge
                f32x4 v = *(const f32x4*)&tile[row][ch * 4];
                __builtin_nontemporal_store(v, (f32x4*)(out + (size_t)rg * NN + cg));
            }
        }
        __syncthreads();
    }
}

// ---------------- host ----------------
extern "C" void kernel_launch(void* const* d_in, const int* in_sizes, int n_in,
                              void* d_out, int out_size, void* d_ws, size_t ws_size,
                              hipStream_t stream) {
    const float* x      = (const float*)d_in[0];
    const int*   ei     = (const int*)d_in[1];
    const float* eps    = (const float*)d_in[2];
    const float* gcn_w  = (const float*)d_in[3];
    const float* gcn_b  = (const float*)d_in[4];
    const float* gat_w  = (const float*)d_in[5];
    const float* att_s  = (const float*)d_in[6];
    const float* att_d  = (const float*)d_in[7];
    const float* gat_b  = (const float*)d_in[8];
    const float* mlp_w1 = (const float*)d_in[9];
    const float* mlp_b1 = (const float*)d_in[10];
    const float* mlp_w2 = (const float*)d_in[11];
    const float* mlp_b2 = (const float*)d_in[12];
    const float* mu_w   = (const float*)d_in[13];
    const float* mu_b   = (const float*)d_in[14];
    const float* lv_w   = (const float*)d_in[15];
    const float* lv_b   = (const float*)d_in[16];
    const float* dec_w1 = (const float*)d_in[17];
    const float* dec_b1 = (const float*)d_in[18];
    const float* dec_w2 = (const float*)d_in[19];
    const float* dec_b2 = (const float*)d_in[20];

    float* out    = (float*)d_out;              // fp32 outputs, concatenated
    float* out_mu = out + (size_t)NN * NN;
    float* out_lv = out_mu + (size_t)NN * 64;

    char* ws = (char*)d_ws;
    size_t off = 0;
    auto alloc = [&](size_t bytes) -> void* {
        void* p = ws + off;
        off += (bytes + 255) & ~(size_t)255;
        return p;
    };
    int*   cnt       = (int*)alloc(NN * 4);
    int*   fill      = (int*)alloc(NN * 4);
    int*   rowptr    = (int*)alloc((NN + 1) * 4);
    int*   csr       = (int*)alloc(EE * 4);
    float* dinv      = (float*)alloc(NN * 4);
    float* a_src     = (float*)alloc(NN * 4 * 4);
    float* a_dst     = (float*)alloc(NN * 4 * 4);
    float* selfalpha = (float*)alloc(NN * 4 * 4);
    float* z         = (float*)alloc((size_t)NN * 64 * 4);
    float* h2        = (float*)alloc((size_t)NN * 128 * 4);
    float* bufA      = (float*)alloc((size_t)NN * 128 * 4);   // h0(bf16), later m1
    float* bufB      = (float*)alloc((size_t)NN * 128 * 4);   // h1, later m2
    float* bufC      = (float*)alloc((size_t)NN * 512 * 4);   // g(bf16), later t1
    float* bufD      = (float*)alloc((size_t)EE * 4 * 4);     // alpha, later dbf

    u16*   h0bf  = (u16*)bufA;
    float* h1    = bufB;
    u16*   gbf   = (u16*)bufC;
    float* alpha = bufD;
    float* m1    = bufA;   // h0 dead after k_gcn_agg
    float* m2    = bufB;   // h1 dead after GAT linear
    float* t1    = bufC;   // g dead after k_gat_agg
    u16*   dbf   = (u16*)bufD;  // alpha dead after k_gat_agg

    const int* src = ei;
    const int* dst = ei + EE;

    hipMemsetAsync(cnt, 0, NN * 4, stream);
    hipMemsetAsync(fill, 0, NN * 4, stream);

    k_hist<<<(EE + 255) / 256, 256, 0, stream>>>(dst, cnt);
    k_dinv<<<(NN + 255) / 256, 256, 0, stream>>>(cnt, dinv);
    k_scan<<<1, 1024, 0, stream>>>(cnt, rowptr);
    k_scatter<<<(EE + 255) / 256, 256, 0, stream>>>(src, dst, rowptr, fill, csr);

    // GCN (bf16 h0 for the gather)
    k_linear<128, 128, false, false, true><<<625, 256, 0, stream>>>(x, gcn_w, nullptr, h0bf);
    k_gcn_agg<<<2500, 256, 0, stream>>>(h0bf, rowptr, csr, dinv, gcn_b, h1);

    // GAT (fused linear + scores; bf16 g for the gather)
    k_gat_linear<<<625, 256, 0, stream>>>(h1, gat_w, att_s, att_d, gbf, a_src, a_dst);
    k_gat_softmax<<<2500, 256, 0, stream>>>(rowptr, csr, a_src, a_dst, alpha, selfalpha);
    k_gat_agg<<<2500, 256, 0, stream>>>(gbf, rowptr, csr, alpha, selfalpha, gat_b, h2);

    // MLP encoder
    k_linear<128, 128, true, true, false><<<625, 256, 0, stream>>>(h2, mlp_w1, mlp_b1, m1);
    k_linear<128, 128, true, true, false><<<625, 256, 0, stream>>>(m1, mlp_w2, mlp_b2, m2);
    k_heads<<<625, 256, 0, stream>>>(m2, mu_w, mu_b, lv_w, lv_b, eps, out_mu, out_lv, z);

    // decoder
    k_linear<64, 128, true, true, false><<<625, 256, 0, stream>>>(z, dec_w1, dec_b1, t1);
    k_dec2<<<625, 256, 0, stream>>>(t1, dec_w2, dec_b2, z, dbf);

    // logits = d @ d^T (fp32 out, nontemporal stores)
    dim3 lgrid((NN + 127) / 128, (NN + 127) / 128);
    k_logits<<<lgrid, 256, 0, stream>>>(dbf, out);
}

// Round 3
// 721.413 us; speedup vs baseline: 1.1120x; 1.0547x over previous
//
#include <hip/hip_runtime.h>
#include <hip/hip_bf16.h>

typedef unsigned short u16;
typedef unsigned int u32;

#define NN 10000
#define EE 320000

typedef __attribute__((ext_vector_type(8))) short short8;
typedef __attribute__((ext_vector_type(4))) float f32x4;

__device__ __forceinline__ u16 f2bfu(float f) {
    u32 x = __float_as_uint(f);
    x += 0x7FFFu + ((x >> 16) & 1u);   // round-to-nearest-even
    return (u16)(x >> 16);
}
__device__ __forceinline__ float bfu2f(u16 u) { return __uint_as_float(((u32)u) << 16); }
__device__ __forceinline__ void ld4f(const float* p, float* o) {
    float4 v = *(const float4*)p; o[0] = v.x; o[1] = v.y; o[2] = v.z; o[3] = v.w;
}

// ---------------- CSR build ----------------
__global__ void k_hist(const int* __restrict__ dst, int* __restrict__ cnt) {
    int e = blockIdx.x * 256 + threadIdx.x;
    if (e < EE) atomicAdd(&cnt[dst[e]], 1);
}

// scan + dinv fused (single block)
__global__ void k_scan(const int* __restrict__ cnt, int* __restrict__ rowptr,
                       float* __restrict__ dinv) {
    __shared__ int sh[1024];
    int t = threadIdx.x;
    int base = t * 10;
    int loc[10], cv[10];
    int s = 0;
    #pragma unroll
    for (int i = 0; i < 10; i++) {
        int idx = base + i;
        int v = (idx < NN) ? cnt[idx] : 0;
        cv[i] = v;
        loc[i] = s; s += v;
    }
    sh[t] = s;
    __syncthreads();
    for (int off = 1; off < 1024; off <<= 1) {
        int v = (t >= off) ? sh[t - off] : 0;
        __syncthreads();
        sh[t] += v;
        __syncthreads();
    }
    int ex = sh[t] - s;   // exclusive base for this thread's chunk
    #pragma unroll
    for (int i = 0; i < 10; i++) {
        int idx = base + i;
        if (idx < NN) {
            rowptr[idx] = ex + loc[i];
            dinv[idx] = 1.f / sqrtf((float)(cv[i] + 1));   // +1 self loop
        }
    }
    if (t == 0) rowptr[NN] = EE;
}

__global__ void k_scatter(const int* __restrict__ src, const int* __restrict__ dst,
                          const int* __restrict__ rowptr, int* __restrict__ fill,
                          int* __restrict__ csr) {
    int e = blockIdx.x * 256 + threadIdx.x;
    if (e < EE) {
        int d = dst[e];
        int pos = rowptr[d] + atomicAdd(&fill[d], 1);
        csr[pos] = src[e];
    }
}

// ---------------- generic dense layer: out[N,M] = act(A[N,K] @ W[K,M] + b) ----------------
template <int K, int M, bool RELU, bool BIAS, bool OB16>
__global__ __launch_bounds__(256) void k_linear(const float* __restrict__ A, const float* __restrict__ W,
                                                const float* __restrict__ Bb, void* __restrict__ outv) {
    constexpr int MC = M / 64;
    int wid = (blockIdx.x * blockDim.x + threadIdx.x) >> 6;
    int lane = threadIdx.x & 63;
    int row0 = wid * 4;
    if (row0 >= NN) return;
    float acc[4][MC];
    #pragma unroll
    for (int i = 0; i < 4; i++)
        #pragma unroll
        for (int j = 0; j < MC; j++) acc[i][j] = 0.f;
    for (int k = 0; k < K; k += 4) {
        float a[4][4];
        #pragma unroll
        for (int i = 0; i < 4; i++) ld4f(A + (size_t)(row0 + i) * K + k, a[i]);
        #pragma unroll
        for (int kk = 0; kk < 4; kk++) {
            float wv[MC];
            #pragma unroll
            for (int j = 0; j < MC; j++) wv[j] = W[(size_t)(k + kk) * M + j * 64 + lane];
            #pragma unroll
            for (int i = 0; i < 4; i++)
                #pragma unroll
                for (int j = 0; j < MC; j++) acc[i][j] += a[i][kk] * wv[j];
        }
    }
    float* outf = (float*)outv;
    u16*   outb = (u16*)outv;
    #pragma unroll
    for (int i = 0; i < 4; i++) {
        int r = row0 + i;
        #pragma unroll
        for (int j = 0; j < MC; j++) {
            float v = acc[i][j];
            if constexpr (BIAS) v += Bb[j * 64 + lane];
            if constexpr (RELU) v = fmaxf(v, 0.f);
            if constexpr (OB16) outb[(size_t)r * M + j * 64 + lane] = f2bfu(v);
            else                outf[(size_t)r * M + j * 64 + lane] = v;
        }
    }
}

// ---------------- GCN aggregation (bf16 gather input, fp32 output) ----------------
__global__ __launch_bounds__(256) void k_gcn_agg(const u16* __restrict__ h0, const int* __restrict__ rowptr,
                                                 const int* __restrict__ csr, const float* __restrict__ dinv,
                                                 const float* __restrict__ bias, float* __restrict__ h1) {
    int node = (blockIdx.x * blockDim.x + threadIdx.x) >> 6;
    int lane = threadIdx.x & 63;
    if (node >= NN) return;
    float di = dinv[node];
    u32 sv = *(const u32*)(h0 + (size_t)node * 128 + lane * 2);
    float acc0 = bfu2f((u16)(sv & 0xffffu)) * di * di;   // self loop
    float acc1 = bfu2f((u16)(sv >> 16)) * di * di;
    int st = rowptr[node], en = rowptr[node + 1];
    for (int p = st; p < en; p++) {
        int s = csr[p];
        float w = dinv[s] * di;
        u32 gv = *(const u32*)(h0 + (size_t)s * 128 + lane * 2);
        acc0 += bfu2f((u16)(gv & 0xffffu)) * w;
        acc1 += bfu2f((u16)(gv >> 16)) * w;
    }
    acc0 = fmaxf(acc0 + bias[lane * 2], 0.f);
    acc1 = fmaxf(acc1 + bias[lane * 2 + 1], 0.f);
    float2 o; o.x = acc0; o.y = acc1;
    *(float2*)(h1 + (size_t)node * 128 + lane * 2) = o;
}

// ---------------- GAT linear: g(bf16) + attention scores fused ----------------
__global__ __launch_bounds__(256) void k_gat_linear(const float* __restrict__ A, const float* __restrict__ W,
                                                    const float* __restrict__ att_s, const float* __restrict__ att_d,
                                                    u16* __restrict__ gbf, float* __restrict__ a_src,
                                                    float* __restrict__ a_dst) {
    int wid = (blockIdx.x * blockDim.x + threadIdx.x) >> 6;
    int lane = threadIdx.x & 63;
    int row0 = wid * 4;
    if (row0 >= NN) return;
    float acc[4][8];
    #pragma unroll
    for (int i = 0; i < 4; i++)
        #pragma unroll
        for (int t = 0; t < 8; t++) acc[i][t] = 0.f;
    for (int k = 0; k < 128; k += 4) {
        float a[4][4];
        #pragma unroll
        for (int i = 0; i < 4; i++) ld4f(A + (size_t)(row0 + i) * 128 + k, a[i]);
        #pragma unroll
        for (int kk = 0; kk < 4; kk++) {
            float wv[8];
            ld4f(W + (size_t)(k + kk) * 512 + lane * 8, wv);
            ld4f(W + (size_t)(k + kk) * 512 + lane * 8 + 4, wv + 4);
            #pragma unroll
            for (int i = 0; i < 4; i++)
                #pragma unroll
                for (int t = 0; t < 8; t++) acc[i][t] += a[i][kk] * wv[t];
        }
    }
    float sv[8], dv[8];
    ld4f(att_s + lane * 8, sv); ld4f(att_s + lane * 8 + 4, sv + 4);
    ld4f(att_d + lane * 8, dv); ld4f(att_d + lane * 8 + 4, dv + 4);
    int head = lane >> 4;
    #pragma unroll
    for (int i = 0; i < 4; i++) {
        int r = row0 + i;
        short8 pk;
        #pragma unroll
        for (int t = 0; t < 8; t++) pk[t] = (short)f2bfu(acc[i][t]);
        *(short8*)(gbf + (size_t)r * 512 + lane * 8) = pk;
        float ps = 0.f, pd = 0.f;
        #pragma unroll
        for (int t = 0; t < 8; t++) { ps += acc[i][t] * sv[t]; pd += acc[i][t] * dv[t]; }
        #pragma unroll
        for (int off = 1; off < 16; off <<= 1) {
            ps += __shfl_xor(ps, off, 64);
            pd += __shfl_xor(pd, off, 64);
        }
        if ((lane & 15) == i) {
            a_src[r * 4 + head] = ps;
            a_dst[r * 4 + head] = pd;
        }
    }
}

// ---------------- GAT fused softmax + aggregation ----------------
// Wave per node. Pass 1: per-head max over incoming scores (edges strided across the
// 16 lanes of each head group). Pass 2: serial gather accumulating Sum(exp*g) and den.
// No alpha buffer at all.
__global__ __launch_bounds__(256) void k_gat_sa(const u16* __restrict__ gbf, const int* __restrict__ rowptr,
                                                const int* __restrict__ csr, const float* __restrict__ a_src,
                                                const float* __restrict__ a_dst, const float* __restrict__ bias,
                                                float* __restrict__ h2) {
    int node = (blockIdx.x * blockDim.x + threadIdx.x) >> 6;
    int lane = threadIdx.x & 63;
    if (node >= NN) return;
    int head = lane >> 4, l15 = lane & 15;
    float ad = a_dst[node * 4 + head];
    float es = a_src[node * 4 + head] + ad;
    es = es > 0.f ? es : 0.2f * es;        // self-loop score
    float m = es;
    int st = rowptr[node], en = rowptr[node + 1];
    // pass 1: max
    for (int p = st + l15; p < en; p += 16) {
        float e = a_src[csr[p] * 4 + head] + ad;
        e = e > 0.f ? e : 0.2f * e;
        m = fmaxf(m, e);
    }
    #pragma unroll
    for (int off = 1; off < 16; off <<= 1) m = fmaxf(m, __shfl_xor(m, off, 64));
    // pass 2: weighted gather; den tracked redundantly per lane (uniform within head group)
    float w0 = __expf(es - m);
    float den = w0;
    float acc[8];
    short8 gs = *(const short8*)(gbf + (size_t)node * 512 + lane * 8);
    #pragma unroll
    for (int t = 0; t < 8; t++) acc[t] = w0 * bfu2f((u16)gs[t]);
    for (int p = st; p < en; p++) {
        int s = csr[p];
        float e = a_src[s * 4 + head] + ad;
        e = e > 0.f ? e : 0.2f * e;
        float w = __expf(e - m);
        den += w;
        short8 gv = *(const short8*)(gbf + (size_t)s * 512 + lane * 8);
        #pragma unroll
        for (int t = 0; t < 8; t++) acc[t] += w * bfu2f((u16)gv[t]);
    }
    float inv = 1.f / den;
    #pragma unroll
    for (int t = 0; t < 8; t++) acc[t] *= inv;
    // mean over heads: lanes {l, l^16, l^32, l^48} hold same dims for the 4 heads
    #pragma unroll
    for (int t = 0; t < 8; t++) {
        acc[t] += __shfl_xor(acc[t], 16, 64);
        acc[t] += __shfl_xor(acc[t], 32, 64);
    }
    if (lane < 16) {
        int d0 = lane * 8;
        float o[8];
        #pragma unroll
        for (int t = 0; t < 8; t++) o[t] = fmaxf(acc[t] * 0.25f + bias[d0 + t], 0.f);
        float4 v0, v1;
        v0.x = o[0]; v0.y = o[1]; v0.z = o[2]; v0.w = o[3];
        v1.x = o[4]; v1.y = o[5]; v1.z = o[6]; v1.w = o[7];
        *(float4*)(h2 + (size_t)node * 128 + d0) = v0;
        *(float4*)(h2 + (size_t)node * 128 + d0 + 4) = v1;
    }
}

// ---------------- fused MLP encoder: h2 -> m1 -> m2 -> mu, lv, z ----------------
// Wave handles 4 rows end-to-end; LDS is the wave-local cross-lane transpose buffer.
// No __syncthreads needed: each wave only touches t[wave][..].
__global__ __launch_bounds__(256) void k_mlp(const float* __restrict__ A,
                                             const float* __restrict__ W1, const float* __restrict__ B1,
                                             const float* __restrict__ W2, const float* __restrict__ B2,
                                             const float* __restrict__ muW, const float* __restrict__ muB,
                                             const float* __restrict__ lvW, const float* __restrict__ lvB,
                                             const float* __restrict__ eps, float* __restrict__ mu_out,
                                             float* __restrict__ lv_out, float* __restrict__ z) {
    __shared__ float t[4][4][128];
    int wave = threadIdx.x >> 6;
    int lane = threadIdx.x & 63;
    int row0 = blockIdx.x * 16 + wave * 4;   // NN % 16 == 0
    // ---- stage 1: m1 = relu(A @ W1 + b1) ----
    float acc[4][2];
    #pragma unroll
    for (int i = 0; i < 4; i++) { acc[i][0] = 0.f; acc[i][1] = 0.f; }
    for (int k = 0; k < 128; k += 4) {
        float a[4][4];
        #pragma unroll
        for (int i = 0; i < 4; i++) ld4f(A + (size_t)(row0 + i) * 128 + k, a[i]);
        #pragma unroll
        for (int kk = 0; kk < 4; kk++) {
            float w0 = W1[(size_t)(k + kk) * 128 + lane];
            float w1 = W1[(size_t)(k + kk) * 128 + 64 + lane];
            #pragma unroll
            for (int i = 0; i < 4; i++) { acc[i][0] += a[i][kk] * w0; acc[i][1] += a[i][kk] * w1; }
        }
    }
    #pragma unroll
    for (int i = 0; i < 4; i++) {
        t[wave][i][lane]      = fmaxf(acc[i][0] + B1[lane], 0.f);
        t[wave][i][64 + lane] = fmaxf(acc[i][1] + B1[64 + lane], 0.f);
    }
    // ---- stage 2: m2 = relu(m1 @ W2 + b2), A-slices from LDS ----
    float acc2[4][2];
    #pragma unroll
    for (int i = 0; i < 4; i++) { acc2[i][0] = 0.f; acc2[i][1] = 0.f; }
    for (int k = 0; k < 128; k += 4) {
        float a[4][4];
        #pragma unroll
        for (int i = 0; i < 4; i++) ld4f(&t[wave][i][k], a[i]);
        #pragma unroll
        for (int kk = 0; kk < 4; kk++) {
            float w0 = W2[(size_t)(k + kk) * 128 + lane];
            float w1 = W2[(size_t)(k + kk) * 128 + 64 + lane];
            #pragma unroll
            for (int i = 0; i < 4; i++) { acc2[i][0] += a[i][kk] * w0; acc2[i][1] += a[i][kk] * w1; }
        }
    }
    #pragma unroll
    for (int i = 0; i < 4; i++) {   // overwrite after all stage-2 reads (program order per wave)
        t[wave][i][lane]      = fmaxf(acc2[i][0] + B2[lane], 0.f);
        t[wave][i][64 + lane] = fmaxf(acc2[i][1] + B2[64 + lane], 0.f);
    }
    // ---- stage 3: heads ----
    float am[4] = {0.f, 0.f, 0.f, 0.f};
    float av[4] = {0.f, 0.f, 0.f, 0.f};
    for (int k = 0; k < 128; k += 4) {
        float a[4][4];
        #pragma unroll
        for (int i = 0; i < 4; i++) ld4f(&t[wave][i][k], a[i]);
        #pragma unroll
        for (int kk = 0; kk < 4; kk++) {
            float wm = muW[(k + kk) * 64 + lane];
            float wl = lvW[(k + kk) * 64 + lane];
            #pragma unroll
            for (int i = 0; i < 4; i++) { am[i] += a[i][kk] * wm; av[i] += a[i][kk] * wl; }
        }
    }
    float bm = muB[lane], bl = lvB[lane];
    #pragma unroll
    for (int i = 0; i < 4; i++) {
        size_t idx = (size_t)(row0 + i) * 64 + lane;
        float mu = am[i] + bm;
        float lv = av[i] + bl;
        mu_out[idx] = mu;
        lv_out[idx] = lv;                               // unclipped logvar is the output
        float c = fminf(fmaxf(lv, -10.f), 10.f);
        z[idx] = mu + eps[idx] * __expf(0.5f * c);
    }
}

// ---------------- fused decoder: z -> t1 -> d(bf16, +residual) ----------------
__global__ __launch_bounds__(256) void k_dec(const float* __restrict__ z,
                                             const float* __restrict__ W1, const float* __restrict__ B1,
                                             const float* __restrict__ W2, const float* __restrict__ B2,
                                             u16* __restrict__ dbf) {
    __shared__ float t[4][4][128];
    int wave = threadIdx.x >> 6;
    int lane = threadIdx.x & 63;
    int row0 = blockIdx.x * 16 + wave * 4;
    // ---- stage 1: t1 = relu(z @ W1 + b1), K=64 M=128 ----
    float acc[4][2];
    #pragma unroll
    for (int i = 0; i < 4; i++) { acc[i][0] = 0.f; acc[i][1] = 0.f; }
    for (int k = 0; k < 64; k += 4) {
        float a[4][4];
        #pragma unroll
        for (int i = 0; i < 4; i++) ld4f(z + (size_t)(row0 + i) * 64 + k, a[i]);
        #pragma unroll
        for (int kk = 0; kk < 4; kk++) {
            float w0 = W1[(size_t)(k + kk) * 128 + lane];
            float w1 = W1[(size_t)(k + kk) * 128 + 64 + lane];
            #pragma unroll
            for (int i = 0; i < 4; i++) { acc[i][0] += a[i][kk] * w0; acc[i][1] += a[i][kk] * w1; }
        }
    }
    #pragma unroll
    for (int i = 0; i < 4; i++) {
        t[wave][i][lane]      = fmaxf(acc[i][0] + B1[lane], 0.f);
        t[wave][i][64 + lane] = fmaxf(acc[i][1] + B1[64 + lane], 0.f);
    }
    // ---- stage 2: d = t1 @ W2 + b2 + z, K=128 M=64, bf16 out ----
    float acc2[4] = {0.f, 0.f, 0.f, 0.f};
    for (int k = 0; k < 128; k += 4) {
        float a[4][4];
        #pragma unroll
        for (int i = 0; i < 4; i++) ld4f(&t[wave][i][k], a[i]);
        #pragma unroll
        for (int kk = 0; kk < 4; kk++) {
            float wv = W2[(size_t)(k + kk) * 64 + lane];
            #pragma unroll
            for (int i = 0; i < 4; i++) acc2[i] += a[i][kk] * wv;
        }
    }
    float b = B2[lane];
    #pragma unroll
    for (int i = 0; i < 4; i++) {
        size_t idx = (size_t)(row0 + i) * 64 + lane;
        dbf[idx] = f2bfu(acc2[i] + b + z[idx]);
    }
}

// ---------------- logits = d @ d^T via MFMA bf16, fp32 output ----------------
__global__ __launch_bounds__(256) void k_logits(const u16* __restrict__ dbf, float* __restrict__ out) {
    __shared__ float tile[64][132];   // half-tile (64 rows), +4 pad keeps float4 alignment
    int tid = threadIdx.x;
    int wave = tid >> 6;
    int lane = tid & 63;
    int l15 = lane & 15, quad = lane >> 4;
    int rowhalf = wave >> 1;          // which 64-row half this wave computes
    int i0 = blockIdx.y * 128 + rowhalf * 64;
    int j0 = blockIdx.x * 128 + (wave & 1) * 64;

    f32x4 acc[4][4];
    #pragma unroll
    for (int r = 0; r < 4; r++)
        #pragma unroll
        for (int c = 0; c < 4; c++) acc[r][c] = (f32x4){0.f, 0.f, 0.f, 0.f};

    #pragma unroll
    for (int ks = 0; ks < 64; ks += 32) {
        short8 a[4], b[4];
        #pragma unroll
        for (int r = 0; r < 4; r++) {
            int row = i0 + r * 16 + l15;
            if (row < NN) a[r] = *(const short8*)(dbf + (size_t)row * 64 + ks + quad * 8);
            else a[r] = (short8){0, 0, 0, 0, 0, 0, 0, 0};
        }
        #pragma unroll
        for (int c = 0; c < 4; c++) {
            int row = j0 + c * 16 + l15;
            if (row < NN) b[c] = *(const short8*)(dbf + (size_t)row * 64 + ks + quad * 8);
            else b[c] = (short8){0, 0, 0, 0, 0, 0, 0, 0};
        }
        #pragma unroll
        for (int r = 0; r < 4; r++)
            #pragma unroll
            for (int c = 0; c < 4; c++)
                acc[r][c] = __builtin_amdgcn_mfma_f32_16x16x32_bf16(a[r], b[c], acc[r][c], 0, 0, 0);
    }

    int lc0 = (wave & 1) * 64;
    #pragma unroll
    for (int chunk = 0; chunk < 2; chunk++) {
        if (rowhalf == chunk) {
            #pragma unroll
            for (int r = 0; r < 4; r++)
                #pragma unroll
                for (int c = 0; c < 4; c++)
                    #pragma unroll
                    for (int v = 0; v < 4; v++)
                        tile[r * 16 + quad * 4 + v][lc0 + c * 16 + l15] = acc[r][c][v];
        }
        __syncthreads();
        #pragma unroll
        for (int it = 0; it < 8; it++) {
            int idx = it * 256 + tid;
            int row = idx >> 5, ch = idx & 31;
            int rg = blockIdx.y * 128 + chunk * 64 + row;
            int cg = blockIdx.x * 128 + ch * 4;
            if (rg < NN && cg < NN) {   // NN % 4 == 0: chunk never straddles the edge
                f32x4 v = *(const f32x4*)&tile[row][ch * 4];
                __builtin_nontemporal_store(v, (f32x4*)(out + (size_t)rg * NN + cg));
            }
        }
        __syncthreads();
    }
}

// ---------------- host ----------------
extern "C" void kernel_launch(void* const* d_in, const int* in_sizes, int n_in,
                              void* d_out, int out_size, void* d_ws, size_t ws_size,
                              hipStream_t stream) {
    const float* x      = (const float*)d_in[0];
    const int*   ei     = (const int*)d_in[1];
    const float* eps    = (const float*)d_in[2];
    const float* gcn_w  = (const float*)d_in[3];
    const float* gcn_b  = (const float*)d_in[4];
    const float* gat_w  = (const float*)d_in[5];
    const float* att_s  = (const float*)d_in[6];
    const float* att_d  = (const float*)d_in[7];
    const float* gat_b  = (const float*)d_in[8];
    const float* mlp_w1 = (const float*)d_in[9];
    const float* mlp_b1 = (const float*)d_in[10];
    const float* mlp_w2 = (const float*)d_in[11];
    const float* mlp_b2 = (const float*)d_in[12];
    const float* mu_w   = (const float*)d_in[13];
    const float* mu_b   = (const float*)d_in[14];
    const float* lv_w   = (const float*)d_in[15];
    const float* lv_b   = (const float*)d_in[16];
    const float* dec_w1 = (const float*)d_in[17];
    const float* dec_b1 = (const float*)d_in[18];
    const float* dec_w2 = (const float*)d_in[19];
    const float* dec_b2 = (const float*)d_in[20];

    float* out    = (float*)d_out;              // fp32 outputs, concatenated
    float* out_mu = out + (size_t)NN * NN;
    float* out_lv = out_mu + (size_t)NN * 64;

    char* ws = (char*)d_ws;
    size_t off = 0;
    auto alloc = [&](size_t bytes) -> void* {
        void* p = ws + off;
        off += (bytes + 255) & ~(size_t)255;
        return p;
    };
    int*   cnt    = (int*)alloc(NN * 4);
    int*   fill   = (int*)alloc(NN * 4);
    int*   rowptr = (int*)alloc((NN + 1) * 4);
    int*   csr    = (int*)alloc(EE * 4);
    float* dinv   = (float*)alloc(NN * 4);
    float* a_src  = (float*)alloc(NN * 4 * 4);
    float* a_dst  = (float*)alloc(NN * 4 * 4);
    float* z      = (float*)alloc((size_t)NN * 64 * 4);
    float* h2     = (float*)alloc((size_t)NN * 128 * 4);
    float* bufA   = (float*)alloc((size_t)NN * 128 * 4);   // h0 (bf16)
    float* bufB   = (float*)alloc((size_t)NN * 128 * 4);   // h1
    float* bufC   = (float*)alloc((size_t)NN * 512 * 4);   // g (bf16)
    float* bufD   = (float*)alloc((size_t)NN * 64 * 2);    // dbf

    u16*   h0bf = (u16*)bufA;
    float* h1   = bufB;
    u16*   gbf  = (u16*)bufC;
    u16*   dbf  = (u16*)bufD;

    const int* src = ei;
    const int* dst = ei + EE;

    hipMemsetAsync(cnt, 0, NN * 4, stream);
    hipMemsetAsync(fill, 0, NN * 4, stream);

    k_hist<<<(EE + 255) / 256, 256, 0, stream>>>(dst, cnt);
    k_scan<<<1, 1024, 0, stream>>>(cnt, rowptr, dinv);
    k_scatter<<<(EE + 255) / 256, 256, 0, stream>>>(src, dst, rowptr, fill, csr);

    // GCN (bf16 h0 for the gather)
    k_linear<128, 128, false, false, true><<<625, 256, 0, stream>>>(x, gcn_w, nullptr, h0bf);
    k_gcn_agg<<<2500, 256, 0, stream>>>(h0bf, rowptr, csr, dinv, gcn_b, h1);

    // GAT (fused linear+scores; fused softmax+aggregation, no alpha buffer)
    k_gat_linear<<<625, 256, 0, stream>>>(h1, gat_w, att_s, att_d, gbf, a_src, a_dst);
    k_gat_sa<<<2500, 256, 0, stream>>>(gbf, rowptr, csr, a_src, a_dst, gat_b, h2);

    // fused MLP encoder (mlp1 -> mlp2 -> mu/lv/z, LDS between stages)
    k_mlp<<<625, 256, 0, stream>>>(h2, mlp_w1, mlp_b1, mlp_w2, mlp_b2,
                                   mu_w, mu_b, lv_w, lv_b, eps, out_mu, out_lv, z);

    // fused decoder (dec1 -> dec2 + residual -> bf16 d)
    k_dec<<<625, 256, 0, stream>>>(z, dec_w1, dec_b1, dec_w2, dec_b2, dbf);

    // logits = d @ d^T (fp32 out, nontemporal stores)
    dim3 lgrid((NN + 127) / 128, (NN + 127) / 128);
    k_logits<<<lgrid, 256, 0, stream>>>(dbf, out);
}

// Round 5
// 698.462 us; speedup vs baseline: 1.1485x; 1.0329x over previous
//
#include <hip/hip_runtime.h>
#include <hip/hip_bf16.h>

typedef unsigned short u16;
typedef unsigned int u32;

#define NN 10000
#define EE 320000

typedef __attribute__((ext_vector_type(8))) short short8;
typedef __attribute__((ext_vector_type(4))) float f32x4;

__device__ __forceinline__ u16 f2bfu(float f) {
    u32 x = __float_as_uint(f);
    x += 0x7FFFu + ((x >> 16) & 1u);   // round-to-nearest-even
    return (u16)(x >> 16);
}
__device__ __forceinline__ float bfu2f(u16 u) { return __uint_as_float(((u32)u) << 16); }
__device__ __forceinline__ void ld4f(const float* p, float* o) {
    float4 v = *(const float4*)p; o[0] = v.x; o[1] = v.y; o[2] = v.z; o[3] = v.w;
}

// ---------------- CSR build ----------------
__global__ void k_hist(const int* __restrict__ dst, int* __restrict__ cnt) {
    int e = blockIdx.x * 256 + threadIdx.x;
    if (e < EE) atomicAdd(&cnt[dst[e]], 1);
}

// scan + dinv fused (single block)
__global__ void k_scan(const int* __restrict__ cnt, int* __restrict__ rowptr,
                       float* __restrict__ dinv) {
    __shared__ int sh[1024];
    int t = threadIdx.x;
    int base = t * 10;
    int loc[10], cv[10];
    int s = 0;
    #pragma unroll
    for (int i = 0; i < 10; i++) {
        int idx = base + i;
        int v = (idx < NN) ? cnt[idx] : 0;
        cv[i] = v;
        loc[i] = s; s += v;
    }
    sh[t] = s;
    __syncthreads();
    for (int off = 1; off < 1024; off <<= 1) {
        int v = (t >= off) ? sh[t - off] : 0;
        __syncthreads();
        sh[t] += v;
        __syncthreads();
    }
    int ex = sh[t] - s;   // exclusive base for this thread's chunk
    #pragma unroll
    for (int i = 0; i < 10; i++) {
        int idx = base + i;
        if (idx < NN) {
            rowptr[idx] = ex + loc[i];
            dinv[idx] = 1.f / sqrtf((float)(cv[i] + 1));   // +1 self loop
        }
    }
    if (t == 0) rowptr[NN] = EE;
}

__global__ void k_scatter(const int* __restrict__ src, const int* __restrict__ dst,
                          const int* __restrict__ rowptr, int* __restrict__ fill,
                          int* __restrict__ csr) {
    int e = blockIdx.x * 256 + threadIdx.x;
    if (e < EE) {
        int d = dst[e];
        int pos = rowptr[d] + atomicAdd(&fill[d], 1);
        csr[pos] = src[e];
    }
}

// ---------------- W^T convert: gat_w [128][512] fp32 -> WT [512][128] bf16 ----------------
__global__ void k_wt(const float* __restrict__ w, u16* __restrict__ wt) {
    int idx = blockIdx.x * 256 + threadIdx.x;
    if (idx < 128 * 512) {
        int k = idx >> 9, j = idx & 511;
        wt[j * 128 + k] = f2bfu(w[idx]);
    }
}

// ---------------- generic dense layer: out[N,M] = act(A[N,K] @ W[K,M] + b) ----------------
template <int K, int M, bool RELU, bool BIAS, bool OB16>
__global__ __launch_bounds__(256) void k_linear(const float* __restrict__ A, const float* __restrict__ W,
                                                const float* __restrict__ Bb, void* __restrict__ outv) {
    constexpr int MC = M / 64;
    int wid = (blockIdx.x * blockDim.x + threadIdx.x) >> 6;
    int lane = threadIdx.x & 63;
    int row0 = wid * 4;
    if (row0 >= NN) return;
    float acc[4][MC];
    #pragma unroll
    for (int i = 0; i < 4; i++)
        #pragma unroll
        for (int j = 0; j < MC; j++) acc[i][j] = 0.f;
    for (int k = 0; k < K; k += 4) {
        float a[4][4];
        #pragma unroll
        for (int i = 0; i < 4; i++) ld4f(A + (size_t)(row0 + i) * K + k, a[i]);
        #pragma unroll
        for (int kk = 0; kk < 4; kk++) {
            float wv[MC];
            #pragma unroll
            for (int j = 0; j < MC; j++) wv[j] = W[(size_t)(k + kk) * M + j * 64 + lane];
            #pragma unroll
            for (int i = 0; i < 4; i++)
                #pragma unroll
                for (int j = 0; j < MC; j++) acc[i][j] += a[i][kk] * wv[j];
        }
    }
    float* outf = (float*)outv;
    u16*   outb = (u16*)outv;
    #pragma unroll
    for (int i = 0; i < 4; i++) {
        int r = row0 + i;
        #pragma unroll
        for (int j = 0; j < MC; j++) {
            float v = acc[i][j];
            if constexpr (BIAS) v += Bb[j * 64 + lane];
            if constexpr (RELU) v = fmaxf(v, 0.f);
            if constexpr (OB16) outb[(size_t)r * M + j * 64 + lane] = f2bfu(v);
            else                outf[(size_t)r * M + j * 64 + lane] = v;
        }
    }
}

// ---------------- GCN aggregation (bf16 gather input, bf16 packed output) ----------------
__global__ __launch_bounds__(256) void k_gcn_agg(const u16* __restrict__ h0, const int* __restrict__ rowptr,
                                                 const int* __restrict__ csr, const float* __restrict__ dinv,
                                                 const float* __restrict__ bias, u16* __restrict__ h1bf) {
    int node = (blockIdx.x * blockDim.x + threadIdx.x) >> 6;
    int lane = threadIdx.x & 63;
    if (node >= NN) return;
    float di = dinv[node];
    u32 sv = *(const u32*)(h0 + (size_t)node * 128 + lane * 2);
    float acc0 = bfu2f((u16)(sv & 0xffffu)) * di * di;   // self loop
    float acc1 = bfu2f((u16)(sv >> 16)) * di * di;
    int st = rowptr[node], en = rowptr[node + 1];
    for (int p = st; p < en; p++) {
        int s = csr[p];
        float w = dinv[s] * di;
        u32 gv = *(const u32*)(h0 + (size_t)s * 128 + lane * 2);
        acc0 += bfu2f((u16)(gv & 0xffffu)) * w;
        acc1 += bfu2f((u16)(gv >> 16)) * w;
    }
    acc0 = fmaxf(acc0 + bias[lane * 2], 0.f);
    acc1 = fmaxf(acc1 + bias[lane * 2 + 1], 0.f);
    u32 pack = (u32)f2bfu(acc0) | ((u32)f2bfu(acc1) << 16);
    *(u32*)(h1bf + (size_t)node * 128 + lane * 2) = pack;
}

// ---------------- GAT linear via MFMA: g = h1 @ W (bf16), fused per-head scores ----------------
// grid (4, 79): blockIdx.x = head (128 cols), blockIdx.y = 128-row tile.
// 4 waves; wave w computes the 64x64 quadrant (rows (w>>1)*64, cols (w&1)*64).
__global__ __launch_bounds__(256) void k_gat_mfma(const u16* __restrict__ h1bf, const u16* __restrict__ wt,
                                                  const float* __restrict__ att_s, const float* __restrict__ att_d,
                                                  u16* __restrict__ gbf, float* __restrict__ a_src,
                                                  float* __restrict__ a_dst) {
    __shared__ u16 gt[128][128];        // 32 KB staging for coalesced g writes
    __shared__ float ssrc[128][2], sdst[128][2];
    int tid = threadIdx.x;
    int wave = tid >> 6;
    int lane = tid & 63;
    int l15 = lane & 15, quad = lane >> 4;
    int h = blockIdx.x;                  // head
    int i0 = blockIdx.y * 128 + (wave >> 1) * 64;   // global row base for this wave
    int jh = (wave & 1) * 64;                        // col base within the head tile

    f32x4 acc[4][4];
    #pragma unroll
    for (int r = 0; r < 4; r++)
        #pragma unroll
        for (int c = 0; c < 4; c++) acc[r][c] = (f32x4){0.f, 0.f, 0.f, 0.f};

    #pragma unroll
    for (int ks = 0; ks < 128; ks += 32) {
        short8 a[4], b[4];
        #pragma unroll
        for (int r = 0; r < 4; r++) {
            int row = i0 + r * 16 + l15;
            if (row < NN) a[r] = *(const short8*)(h1bf + (size_t)row * 128 + ks + quad * 8);
            else a[r] = (short8){0, 0, 0, 0, 0, 0, 0, 0};
        }
        #pragma unroll
        for (int c = 0; c < 4; c++) {
            int col = h * 128 + jh + c * 16 + l15;   // global output column in [0,512)
            b[c] = *(const short8*)(wt + (size_t)col * 128 + ks + quad * 8);
        }
        #pragma unroll
        for (int r = 0; r < 4; r++)
            #pragma unroll
            for (int c = 0; c < 4; c++)
                acc[r][c] = __builtin_amdgcn_mfma_f32_16x16x32_bf16(a[r], b[c], acc[r][c], 0, 0, 0);
    }

    // epilogue A: per-row partial scores for this wave's 64 cols (head h)
    // C layout: local row = r*16 + quad*4 + v, local col = c*16 + l15
    float as_v[4], ad_v[4];
    #pragma unroll
    for (int c = 0; c < 4; c++) {
        as_v[c] = att_s[h * 128 + jh + c * 16 + l15];
        ad_v[c] = att_d[h * 128 + jh + c * 16 + l15];
    }
    #pragma unroll
    for (int r = 0; r < 4; r++) {
        #pragma unroll
        for (int v = 0; v < 4; v++) {
            float ps = 0.f, pd = 0.f;
            #pragma unroll
            for (int c = 0; c < 4; c++) {
                float x = acc[r][c][v];
                ps += x * as_v[c];
                pd += x * ad_v[c];
            }
            #pragma unroll
            for (int off = 1; off < 16; off <<= 1) {
                ps += __shfl_xor(ps, off, 64);
                pd += __shfl_xor(pd, off, 64);
            }
            if (l15 == 0) {
                int lr = (wave >> 1) * 64 + r * 16 + quad * 4 + v;
                ssrc[lr][wave & 1] = ps;
                sdst[lr][wave & 1] = pd;
            }
        }
    }
    // epilogue B: g -> bf16 LDS tile
    #pragma unroll
    for (int r = 0; r < 4; r++)
        #pragma unroll
        for (int c = 0; c < 4; c++)
            #pragma unroll
            for (int v = 0; v < 4; v++)
                gt[(wave >> 1) * 64 + r * 16 + quad * 4 + v][jh + c * 16 + l15] = f2bfu(acc[r][c][v]);
    __syncthreads();

    // scores out: 128 rows, one thread per row
    if (tid < 128) {
        int row = blockIdx.y * 128 + tid;
        if (row < NN) {
            a_src[row * 4 + h] = ssrc[tid][0] + ssrc[tid][1];
            a_dst[row * 4 + h] = sdst[tid][0] + sdst[tid][1];
        }
    }
    // g out: 128 rows x 256 B (this head's slice), short8 chunks
    #pragma unroll
    for (int it = 0; it < 8; it++) {
        int idx = it * 256 + tid;
        int row = idx >> 4, ch = idx & 15;
        int rg = blockIdx.y * 128 + row;
        if (rg < NN) {
            short8 v = *(const short8*)&gt[row][ch * 8];
            *(short8*)(gbf + (size_t)rg * 512 + h * 128 + ch * 8) = v;
        }
    }
}

// ---------------- GAT fused single-pass online softmax + aggregation ----------------
// Wave per node; head = lane>>4. Running max m with rescale-on-growth (exact softmax identity).
__global__ __launch_bounds__(256) void k_gat_sa(const u16* __restrict__ gbf, const int* __restrict__ rowptr,
                                                const int* __restrict__ csr, const float* __restrict__ a_src,
                                                const float* __restrict__ a_dst, const float* __restrict__ bias,
                                                float* __restrict__ h2) {
    int node = (blockIdx.x * blockDim.x + threadIdx.x) >> 6;
    int lane = threadIdx.x & 63;
    if (node >= NN) return;
    int head = lane >> 4;
    float ad = a_dst[node * 4 + head];
    float es = a_src[node * 4 + head] + ad;
    es = es > 0.f ? es : 0.2f * es;        // self-loop score
    float m = es;
    float den = 1.f;                        // exp(es - m) = 1
    float acc[8];
    short8 gs = *(const short8*)(gbf + (size_t)node * 512 + lane * 8);
    #pragma unroll
    for (int t = 0; t < 8; t++) acc[t] = bfu2f((u16)gs[t]);
    int st = rowptr[node], en = rowptr[node + 1];
    for (int p = st; p < en; p++) {
        int s = csr[p];
        float e = a_src[s * 4 + head] + ad;
        e = e > 0.f ? e : 0.2f * e;
        if (e > m) {                        // rescale old state (rare after warmup)
            float sc = __expf(m - e);
            den *= sc;
            #pragma unroll
            for (int t = 0; t < 8; t++) acc[t] *= sc;
            m = e;
        }
        float w = __expf(e - m);
        den += w;
        short8 gv = *(const short8*)(gbf + (size_t)s * 512 + lane * 8);
        #pragma unroll
        for (int t = 0; t < 8; t++) acc[t] += w * bfu2f((u16)gv[t]);
    }
    float inv = 1.f / den;
    #pragma unroll
    for (int t = 0; t < 8; t++) acc[t] *= inv;
    // mean over heads: lanes {l, l^16, l^32, l^48} hold same dims for the 4 heads
    #pragma unroll
    for (int t = 0; t < 8; t++) {
        acc[t] += __shfl_xor(acc[t], 16, 64);
        acc[t] += __shfl_xor(acc[t], 32, 64);
    }
    if (lane < 16) {
        int d0 = lane * 8;
        float o[8];
        #pragma unroll
        for (int t = 0; t < 8; t++) o[t] = fmaxf(acc[t] * 0.25f + bias[d0 + t], 0.f);
        float4 v0, v1;
        v0.x = o[0]; v0.y = o[1]; v0.z = o[2]; v0.w = o[3];
        v1.x = o[4]; v1.y = o[5]; v1.z = o[6]; v1.w = o[7];
        *(float4*)(h2 + (size_t)node * 128 + d0) = v0;
        *(float4*)(h2 + (size_t)node * 128 + d0 + 4) = v1;
    }
}

// ---------------- fused MLP encoder: h2 -> m1 -> m2 -> mu, lv, z ----------------
__global__ __launch_bounds__(256) void k_mlp(const float* __restrict__ A,
                                             const float* __restrict__ W1, const float* __restrict__ B1,
                                             const float* __restrict__ W2, const float* __restrict__ B2,
                                             const float* __restrict__ muW, const float* __restrict__ muB,
                                             const float* __restrict__ lvW, const float* __restrict__ lvB,
                                             const float* __restrict__ eps, float* __restrict__ mu_out,
                                             float* __restrict__ lv_out, float* __restrict__ z) {
    __shared__ float t[4][4][128];
    int wave = threadIdx.x >> 6;
    int lane = threadIdx.x & 63;
    int row0 = blockIdx.x * 16 + wave * 4;   // NN % 16 == 0
    // ---- stage 1: m1 = relu(A @ W1 + b1) ----
    float acc[4][2];
    #pragma unroll
    for (int i = 0; i < 4; i++) { acc[i][0] = 0.f; acc[i][1] = 0.f; }
    for (int k = 0; k < 128; k += 4) {
        float a[4][4];
        #pragma unroll
        for (int i = 0; i < 4; i++) ld4f(A + (size_t)(row0 + i) * 128 + k, a[i]);
        #pragma unroll
        for (int kk = 0; kk < 4; kk++) {
            float w0 = W1[(size_t)(k + kk) * 128 + lane];
            float w1 = W1[(size_t)(k + kk) * 128 + 64 + lane];
            #pragma unroll
            for (int i = 0; i < 4; i++) { acc[i][0] += a[i][kk] * w0; acc[i][1] += a[i][kk] * w1; }
        }
    }
    #pragma unroll
    for (int i = 0; i < 4; i++) {
        t[wave][i][lane]      = fmaxf(acc[i][0] + B1[lane], 0.f);
        t[wave][i][64 + lane] = fmaxf(acc[i][1] + B1[64 + lane], 0.f);
    }
    // ---- stage 2: m2 = relu(m1 @ W2 + b2), A-slices from LDS ----
    float acc2[4][2];
    #pragma unroll
    for (int i = 0; i < 4; i++) { acc2[i][0] = 0.f; acc2[i][1] = 0.f; }
    for (int k = 0; k < 128; k += 4) {
        float a[4][4];
        #pragma unroll
        for (int i = 0; i < 4; i++) ld4f(&t[wave][i][k], a[i]);
        #pragma unroll
        for (int kk = 0; kk < 4; kk++) {
            float w0 = W2[(size_t)(k + kk) * 128 + lane];
            float w1 = W2[(size_t)(k + kk) * 128 + 64 + lane];
            #pragma unroll
            for (int i = 0; i < 4; i++) { acc2[i][0] += a[i][kk] * w0; acc2[i][1] += a[i][kk] * w1; }
        }
    }
    #pragma unroll
    for (int i = 0; i < 4; i++) {   // overwrite after all stage-2 reads (program order per wave)
        t[wave][i][lane]      = fmaxf(acc2[i][0] + B2[lane], 0.f);
        t[wave][i][64 + lane] = fmaxf(acc2[i][1] + B2[64 + lane], 0.f);
    }
    // ---- stage 3: heads ----
    float am[4] = {0.f, 0.f, 0.f, 0.f};
    float av[4] = {0.f, 0.f, 0.f, 0.f};
    for (int k = 0; k < 128; k += 4) {
        float a[4][4];
        #pragma unroll
        for (int i = 0; i < 4; i++) ld4f(&t[wave][i][k], a[i]);
        #pragma unroll
        for (int kk = 0; kk < 4; kk++) {
            float wm = muW[(k + kk) * 64 + lane];
            float wl = lvW[(k + kk) * 64 + lane];
            #pragma unroll
            for (int i = 0; i < 4; i++) { am[i] += a[i][kk] * wm; av[i] += a[i][kk] * wl; }
        }
    }
    float bm = muB[lane], bl = lvB[lane];
    #pragma unroll
    for (int i = 0; i < 4; i++) {
        size_t idx = (size_t)(row0 + i) * 64 + lane;
        float mu = am[i] + bm;
        float lv = av[i] + bl;
        mu_out[idx] = mu;
        lv_out[idx] = lv;                               // unclipped logvar is the output
        float c = fminf(fmaxf(lv, -10.f), 10.f);
        z[idx] = mu + eps[idx] * __expf(0.5f * c);
    }
}

// ---------------- fused decoder: z -> t1 -> d(bf16, +residual) ----------------
__global__ __launch_bounds__(256) void k_dec(const float* __restrict__ z,
                                             const float* __restrict__ W1, const float* __restrict__ B1,
                                             const float* __restrict__ W2, const float* __restrict__ B2,
                                             u16* __restrict__ dbf) {
    __shared__ float t[4][4][128];
    int wave = threadIdx.x >> 6;
    int lane = threadIdx.x & 63;
    int row0 = blockIdx.x * 16 + wave * 4;
    // ---- stage 1: t1 = relu(z @ W1 + b1), K=64 M=128 ----
    float acc[4][2];
    #pragma unroll
    for (int i = 0; i < 4; i++) { acc[i][0] = 0.f; acc[i][1] = 0.f; }
    for (int k = 0; k < 64; k += 4) {
        float a[4][4];
        #pragma unroll
        for (int i = 0; i < 4; i++) ld4f(z + (size_t)(row0 + i) * 64 + k, a[i]);
        #pragma unroll
        for (int kk = 0; kk < 4; kk++) {
            float w0 = W1[(size_t)(k + kk) * 128 + lane];
            float w1 = W1[(size_t)(k + kk) * 128 + 64 + lane];
            #pragma unroll
            for (int i = 0; i < 4; i++) { acc[i][0] += a[i][kk] * w0; acc[i][1] += a[i][kk] * w1; }
        }
    }
    #pragma unroll
    for (int i = 0; i < 4; i++) {
        t[wave][i][lane]      = fmaxf(acc[i][0] + B1[lane], 0.f);
        t[wave][i][64 + lane] = fmaxf(acc[i][1] + B1[64 + lane], 0.f);
    }
    // ---- stage 2: d = t1 @ W2 + b2 + z, K=128 M=64, bf16 out ----
    float acc2[4] = {0.f, 0.f, 0.f, 0.f};
    for (int k = 0; k < 128; k += 4) {
        float a[4][4];
        #pragma unroll
        for (int i = 0; i < 4; i++) ld4f(&t[wave][i][k], a[i]);
        #pragma unroll
        for (int kk = 0; kk < 4; kk++) {
            float wv = W2[(size_t)(k + kk) * 64 + lane];
            #pragma unroll
            for (int i = 0; i < 4; i++) acc2[i] += a[i][kk] * wv;
        }
    }
    float b = B2[lane];
    #pragma unroll
    for (int i = 0; i < 4; i++) {
        size_t idx = (size_t)(row0 + i) * 64 + lane;
        dbf[idx] = f2bfu(acc2[i] + b + z[idx]);
    }
}

// ---------------- logits = d @ d^T via MFMA bf16, fp32 output ----------------
__global__ __launch_bounds__(256) void k_logits(const u16* __restrict__ dbf, float* __restrict__ out) {
    __shared__ float tile[64][132];   // half-tile (64 rows), +4 pad keeps float4 alignment
    int tid = threadIdx.x;
    int wave = tid >> 6;
    int lane = tid & 63;
    int l15 = lane & 15, quad = lane >> 4;
    int rowhalf = wave >> 1;          // which 64-row half this wave computes
    int i0 = blockIdx.y * 128 + rowhalf * 64;
    int j0 = blockIdx.x * 128 + (wave & 1) * 64;

    f32x4 acc[4][4];
    #pragma unroll
    for (int r = 0; r < 4; r++)
        #pragma unroll
        for (int c = 0; c < 4; c++) acc[r][c] = (f32x4){0.f, 0.f, 0.f, 0.f};

    #pragma unroll
    for (int ks = 0; ks < 64; ks += 32) {
        short8 a[4], b[4];
        #pragma unroll
        for (int r = 0; r < 4; r++) {
            int row = i0 + r * 16 + l15;
            if (row < NN) a[r] = *(const short8*)(dbf + (size_t)row * 64 + ks + quad * 8);
            else a[r] = (short8){0, 0, 0, 0, 0, 0, 0, 0};
        }
        #pragma unroll
        for (int c = 0; c < 4; c++) {
            int row = j0 + c * 16 + l15;
            if (row < NN) b[c] = *(const short8*)(dbf + (size_t)row * 64 + ks + quad * 8);
            else b[c] = (short8){0, 0, 0, 0, 0, 0, 0, 0};
        }
        #pragma unroll
        for (int r = 0; r < 4; r++)
            #pragma unroll
            for (int c = 0; c < 4; c++)
                acc[r][c] = __builtin_amdgcn_mfma_f32_16x16x32_bf16(a[r], b[c], acc[r][c], 0, 0, 0);
    }

    int lc0 = (wave & 1) * 64;
    #pragma unroll
    for (int chunk = 0; chunk < 2; chunk++) {
        if (rowhalf == chunk) {
            #pragma unroll
            for (int r = 0; r < 4; r++)
                #pragma unroll
                for (int c = 0; c < 4; c++)
                    #pragma unroll
                    for (int v = 0; v < 4; v++)
                        tile[r * 16 + quad * 4 + v][lc0 + c * 16 + l15] = acc[r][c][v];
        }
        __syncthreads();
        #pragma unroll
        for (int it = 0; it < 8; it++) {
            int idx = it * 256 + tid;
            int row = idx >> 5, ch = idx & 31;
            int rg = blockIdx.y * 128 + chunk * 64 + row;
            int cg = blockIdx.x * 128 + ch * 4;
            if (rg < NN && cg < NN) {   // NN % 4 == 0: chunk never straddles the edge
                f32x4 v = *(const f32x4*)&tile[row][ch * 4];
                __builtin_nontemporal_store(v, (f32x4*)(out + (size_t)rg * NN + cg));
            }
        }
        __syncthreads();
    }
}

// ---------------- host ----------------
extern "C" void kernel_launch(void* const* d_in, const int* in_sizes, int n_in,
                              void* d_out, int out_size, void* d_ws, size_t ws_size,
                              hipStream_t stream) {
    const float* x      = (const float*)d_in[0];
    const int*   ei     = (const int*)d_in[1];
    const float* eps    = (const float*)d_in[2];
    const float* gcn_w  = (const float*)d_in[3];
    const float* gcn_b  = (const float*)d_in[4];
    const float* gat_w  = (const float*)d_in[5];
    const float* att_s  = (const float*)d_in[6];
    const float* att_d  = (const float*)d_in[7];
    const float* gat_b  = (const float*)d_in[8];
    const float* mlp_w1 = (const float*)d_in[9];
    const float* mlp_b1 = (const float*)d_in[10];
    const float* mlp_w2 = (const float*)d_in[11];
    const float* mlp_b2 = (const float*)d_in[12];
    const float* mu_w   = (const float*)d_in[13];
    const float* mu_b   = (const float*)d_in[14];
    const float* lv_w   = (const float*)d_in[15];
    const float* lv_b   = (const float*)d_in[16];
    const float* dec_w1 = (const float*)d_in[17];
    const float* dec_b1 = (const float*)d_in[18];
    const float* dec_w2 = (const float*)d_in[19];
    const float* dec_b2 = (const float*)d_in[20];

    float* out    = (float*)d_out;              // fp32 outputs, concatenated
    float* out_mu = out + (size_t)NN * NN;
    float* out_lv = out_mu + (size_t)NN * 64;

    char* ws = (char*)d_ws;
    size_t off = 0;
    auto alloc = [&](size_t bytes) -> void* {
        void* p = ws + off;
        off += (bytes + 255) & ~(size_t)255;
        return p;
    };
    int*   cnt    = (int*)alloc(NN * 4);
    int*   fill   = (int*)alloc(NN * 4);
    int*   rowptr = (int*)alloc((NN + 1) * 4);
    int*   csr    = (int*)alloc(EE * 4);
    float* dinv   = (float*)alloc(NN * 4);
    float* a_src  = (float*)alloc(NN * 4 * 4);
    float* a_dst  = (float*)alloc(NN * 4 * 4);
    float* z      = (float*)alloc((size_t)NN * 64 * 4);
    float* h2     = (float*)alloc((size_t)NN * 128 * 4);
    u16*   wt     = (u16*)alloc(512 * 128 * 2);            // gat_w^T bf16
    u16*   h0bf   = (u16*)alloc((size_t)NN * 128 * 2);
    u16*   h1bf   = (u16*)alloc((size_t)NN * 128 * 2);
    u16*   gbf    = (u16*)alloc((size_t)NN * 512 * 2);
    u16*   dbf    = (u16*)alloc((size_t)NN * 64 * 2);

    const int* src = ei;
    const int* dst = ei + EE;

    hipMemsetAsync(cnt, 0, NN * 4, stream);
    hipMemsetAsync(fill, 0, NN * 4, stream);

    k_wt<<<(128 * 512 + 255) / 256, 256, 0, stream>>>(gat_w, wt);
    k_hist<<<(EE + 255) / 256, 256, 0, stream>>>(dst, cnt);
    k_scan<<<1, 1024, 0, stream>>>(cnt, rowptr, dinv);
    k_scatter<<<(EE + 255) / 256, 256, 0, stream>>>(src, dst, rowptr, fill, csr);

    // GCN (bf16 h0 for the gather; bf16 packed h1 for the MFMA GAT linear)
    k_linear<128, 128, false, false, true><<<625, 256, 0, stream>>>(x, gcn_w, nullptr, h0bf);
    k_gcn_agg<<<2500, 256, 0, stream>>>(h0bf, rowptr, csr, dinv, gcn_b, h1bf);

    // GAT: MFMA linear with fused per-head scores; single-pass online softmax+agg
    dim3 ggrid(4, (NN + 127) / 128);
    k_gat_mfma<<<ggrid, 256, 0, stream>>>(h1bf, wt, att_s, att_d, gbf, a_src, a_dst);
    k_gat_sa<<<2500, 256, 0, stream>>>(gbf, rowptr, csr, a_src, a_dst, gat_b, h2);

    // fused MLP encoder (mlp1 -> mlp2 -> mu/lv/z, LDS between stages)
    k_mlp<<<625, 256, 0, stream>>>(h2, mlp_w1, mlp_b1, mlp_w2, mlp_b2,
                                   mu_w, mu_b, lv_w, lv_b, eps, out_mu, out_lv, z);

    // fused decoder (dec1 -> dec2 + residual -> bf16 d)
    k_dec<<<625, 256, 0, stream>>>(z, dec_w1, dec_b1, dec_w2, dec_b2, dbf);

    // logits = d @ d^T (fp32 out, nontemporal stores)
    dim3 lgrid((NN + 127) / 128, (NN + 127) / 128);
    k_logits<<<lgrid, 256, 0, stream>>>(dbf, out);
}